// Round 13
// baseline (493.069 us; speedup 1.0000x reference)
//
#include <hip/hip_runtime.h>

// GraphAttentionEmbedding: 2x TransformerConv (PyG) on MI355X (gfx950).
// N=50000, E=400000, IN=128, H1=8*16=128, OUT=128, EDIM=32.
// PROVEN: fp32 inputs (runtime-detected), fp32 output; internal bf16+fp32 acc.
// GEMM lesson (R7-R10): LDS-staged A+B, one weight set per block = fast form.
// R12: DPP reductions (attn 71->sub-61), 3-phase scan. R13: operand-swapped
// MFMA (lane acc = 4 consecutive out-cols -> uint2 epilogue), k/v interleaved
// buffer (attn gather: one uint2 per edge), split srcs/eids arrays.

using u16 = unsigned short;
using u32 = unsigned int;

#define NODES 50000
#define EDGES 400000
#define NB196 196   // ceil(50000/256)

typedef __attribute__((ext_vector_type(8))) short bf16x8;
typedef __attribute__((ext_vector_type(4))) float f32x4;

__device__ __forceinline__ float bflo(u32 u) { return __uint_as_float(u << 16); }
__device__ __forceinline__ float bfhi(u32 u) { return __uint_as_float(u & 0xffff0000u); }
__device__ __forceinline__ u16 f2bf(float f) {
    u32 u = __float_as_uint(f);
    u += 0x7fffu + ((u >> 16) & 1u);   // RNE
    return (u16)(u >> 16);
}
__device__ __forceinline__ u32 pack2(float a, float b) {
    return (u32)f2bf(a) | ((u32)f2bf(b) << 16);
}

// DPP lane-add at VALU speed (no DS pipe).
template <int CTRL>
__device__ __forceinline__ float dpp_addf(float x) {
    int y = __builtin_amdgcn_update_dpp(0, __float_as_int(x), CTRL, 0xF, 0xF, true);
    return x + __int_as_float(y);
}
template <int GRP>
__device__ __forceinline__ float grp_sum(float p, int lane) {
    p = dpp_addf<0xB1>(p);    // xor 1
    p = dpp_addf<0x4E>(p);    // xor 2
    p = dpp_addf<0x141>(p);   // xor 4 (8-group done)
    if (GRP == 64) {
        p = dpp_addf<0x140>(p);   // xor 8
        p += __int_as_float(__builtin_amdgcn_ds_swizzle(__float_as_int(p), 0x401F)); // xor16
        p += __int_as_float(__builtin_amdgcn_ds_bpermute((lane ^ 32) << 2,
                                                         __float_as_int(p)));        // xor32
    }
    return p;
}

// ---------------- diagnostic sentinel (fp32 out) ----------------------------
__global__ __launch_bounds__(256) void fill_sentinel(float* __restrict__ out, int n, float val) {
    int i = blockIdx.x * 256 + threadIdx.x;
    if (i < n) out[i] = val;
}

// ---------------- runtime format detection (one wave) -----------------------
__global__ __launch_bounds__(64) void detect_fmt(const u32* __restrict__ xw,
                                                 const int* __restrict__ eraw,
                                                 int* __restrict__ flags) {
    int lane = threadIdx.x;
    u32 e = (xw[lane] >> 7) & 0xffu;
    unsigned long long sane = __ballot(e >= 90u && e <= 141u);
    unsigned long long zodd = __ballot(eraw[1 + 2 * lane] == 0);
    if (lane == 0) {
        flags[0] = (sane == ~0ull) ? 0 : 1;   // 1 = fp32
        flags[1] = (zodd == ~0ull) ? 1 : 0;   // 1 = int64
    }
}

// ---------------- weight transpose+convert: W[K][128] -> Wt[128][K] bf16 ----
struct TPtrs {
    const void* src[10];
    u16*        dst[10];
    int         K[10];
};

__global__ __launch_bounds__(256) void transpose_w(TPtrs P, const int* __restrict__ fmt) {
    int m = blockIdx.x;
    int f = *fmt;
    int K = P.K[m];
    int quarter = (K * 128) >> 2;
    u16* d = P.dst[m];
    int base = blockIdx.y * quarter;
    const float* sf = (const float*)P.src[m];
    const u16*   sb = (const u16*)P.src[m];
    for (int idx = base + threadIdx.x; idx < base + quarter; idx += 256) {
        int k = idx >> 7, n = idx & 127;
        d[n * K + k] = f ? f2bf(sf[idx]) : sb[idx];
    }
}

// ---------------- CSR build (by dst) ----------------------------------------
__global__ __launch_bounds__(256) void count_deg(const int* __restrict__ raw,
                                                 const int* __restrict__ flags,
                                                 int* __restrict__ deg, int E) {
    int e = blockIdx.x * 256 + threadIdx.x;
    if (e < E) {
        int f = flags[1];
        int d = f ? raw[2 * (E + e)] : raw[E + e];
        if ((unsigned)d < (unsigned)NODES) atomicAdd(&deg[d], 1);
    }
}

__device__ __forceinline__ int block_scan256(int v) {
    __shared__ int ws[4];
    int t = threadIdx.x, lane = t & 63, w = t >> 6;
    int x = v;
#pragma unroll
    for (int off = 1; off < 64; off <<= 1) {
        int y = __shfl_up(x, off, 64);
        if (lane >= off) x += y;
    }
    if (lane == 63) ws[w] = x;
    __syncthreads();
#pragma unroll
    for (int j = 0; j < 3; ++j)
        if (j < w) x += ws[j];
    return x;
}

__global__ __launch_bounds__(256) void scan_a(const int* __restrict__ deg,
                                              int* __restrict__ bsum, int n) {
    int i = blockIdx.x * 256 + threadIdx.x;
    int v = (i < n) ? deg[i] : 0;
    int incl = block_scan256(v);
    if (threadIdx.x == 255) bsum[blockIdx.x] = incl;
}

__global__ __launch_bounds__(256) void scan_b(int* __restrict__ bsum, int nb) {
    int t = threadIdx.x;
    int v = (t < nb) ? bsum[t] : 0;
    int incl = block_scan256(v);
    if (t < nb) bsum[t] = incl - v;
}

__global__ __launch_bounds__(256) void scan_c(const int* __restrict__ deg,
                                              const int* __restrict__ bsum,
                                              int* __restrict__ row_ptr,
                                              int* __restrict__ cursor, int n) {
    int b = blockIdx.x;
    int i = b * 256 + threadIdx.x;
    int v = (i < n) ? deg[i] : 0;
    int incl = block_scan256(v) + bsum[b];
    if (i < n) {
        row_ptr[i + 1] = incl;
        cursor[i] = incl - v;
    }
    if (i == 0) row_ptr[0] = 0;
}

__global__ __launch_bounds__(256) void fill_csr(const int* __restrict__ raw,
                                                const int* __restrict__ flags,
                                                int* __restrict__ cursor,
                                                int* __restrict__ srcs,
                                                int* __restrict__ eids, int E) {
    int e = blockIdx.x * 256 + threadIdx.x;
    if (e < E) {
        int f = flags[1];
        int d = f ? raw[2 * (E + e)] : raw[E + e];
        int s = f ? raw[2 * e] : raw[e];
        if ((unsigned)d < (unsigned)NODES && (unsigned)s < (unsigned)NODES) {
            int pos = atomicAdd(&cursor[d], 1);
            if ((unsigned)pos < (unsigned)E) { srcs[pos] = s; eids[pos] = e; }
        }
    }
}

// ---------------- GEMM: 4 projections, operand-swapped MFMA -----------------
// set 0 = q -> Oq[row][col] (uint2 stores), set 1 = k -> KVo[row][col*2],
// set 2 = v -> KVo[row][col*2+1], set 3 = skip -> Osk[row][col] (uint2).
// Swap: A-operand = Wt rows (out-cols), B-operand = x-row frags.
// D: col(lane&15)=x-row-in-group, row(quad*4+reg)=out-col -> lane holds 4
// consecutive out-cols of one row.
__global__ __launch_bounds__(256) void gemm128(
    const void* __restrict__ A, const int* __restrict__ flags, int a_raw,
    const u16* __restrict__ Wt0, const u16* __restrict__ Wt1,
    const u16* __restrict__ Wt2, const u16* __restrict__ Wt3,
    const void* __restrict__ b0, const void* __restrict__ b1,
    const void* __restrict__ b2, const void* __restrict__ b3,
    u16* __restrict__ Oq, u16* __restrict__ KVo, u16* __restrict__ Osk,
    int M) {
    constexpr int K = 128;
    constexpr int PAD = K + 8;
    constexpr int KV = K / 8;
    __shared__ u16 Asl[64 * PAD];
    __shared__ u16 Bsl[128 * PAD];

    int f = flags[0];
    int set = blockIdx.y;
    const u16* Wt; const void* bias;
    switch (set) {
        case 0: Wt = Wt0; bias = b0; break;
        case 1: Wt = Wt1; bias = b1; break;
        case 2: Wt = Wt2; bias = b2; break;
        default: Wt = Wt3; bias = b3; break;
    }
    int m0 = blockIdx.x * 64;

    if (a_raw && f) {
        const float* Af = (const float*)A;
        for (int idx = threadIdx.x; idx < 64 * KV; idx += 256) {
            int r = idx / KV, cv = idx % KV;
            int gr = m0 + r;
            uint4 val = make_uint4(0, 0, 0, 0);
            if (gr < M) {
                const float* p = Af + (size_t)gr * K + cv * 8;
                float4 lo = *reinterpret_cast<const float4*>(p);
                float4 hi = *reinterpret_cast<const float4*>(p + 4);
                val = make_uint4(pack2(lo.x, lo.y), pack2(lo.z, lo.w),
                                 pack2(hi.x, hi.y), pack2(hi.z, hi.w));
            }
            *reinterpret_cast<uint4*>(&Asl[r * PAD + cv * 8]) = val;
        }
    } else {
        const u16* Ab = (const u16*)A;
        for (int idx = threadIdx.x; idx < 64 * KV; idx += 256) {
            int r = idx / KV, cv = idx % KV;
            int gr = m0 + r;
            uint4 val = make_uint4(0, 0, 0, 0);
            if (gr < M) val = *reinterpret_cast<const uint4*>(Ab + (size_t)gr * K + cv * 8);
            *reinterpret_cast<uint4*>(&Asl[r * PAD + cv * 8]) = val;
        }
    }
    for (int idx = threadIdx.x; idx < 128 * KV; idx += 256) {
        int r = idx / KV, cv = idx % KV;
        *reinterpret_cast<uint4*>(&Bsl[r * PAD + cv * 8]) =
            *reinterpret_cast<const uint4*>(Wt + r * K + cv * 8);
    }
    __syncthreads();

    int lane = threadIdx.x & 63, wv = threadIdx.x >> 6;
    int l15 = lane & 15;
    int quad = lane >> 4;
    int kq = quad * 8;

    // bias for this lane's 4 out-cols per nt: col0 = nt*16 + quad*4
    f32x4 b4[8];
#pragma unroll
    for (int nt = 0; nt < 8; ++nt) {
        int col0 = nt * 16 + quad * 4;
        if (bias) {
            if (f) {
                b4[nt] = *reinterpret_cast<const f32x4*>((const float*)bias + col0);
            } else {
                uint2 bu = *reinterpret_cast<const uint2*>((const u16*)bias + col0);
                b4[nt][0] = bflo(bu.x); b4[nt][1] = bfhi(bu.x);
                b4[nt][2] = bflo(bu.y); b4[nt][3] = bfhi(bu.y);
            }
        } else {
            b4[nt][0] = b4[nt][1] = b4[nt][2] = b4[nt][3] = 0.f;
        }
    }

    f32x4 acc[8] = {};
#pragma unroll
    for (int k0 = 0; k0 < K; k0 += 32) {
        bf16x8 xf = *reinterpret_cast<const bf16x8*>(&Asl[(wv * 16 + l15) * PAD + k0 + kq]);
#pragma unroll
        for (int nt = 0; nt < 8; ++nt) {
            bf16x8 wf = *reinterpret_cast<const bf16x8*>(&Bsl[(nt * 16 + l15) * PAD + k0 + kq]);
            acc[nt] = __builtin_amdgcn_mfma_f32_16x16x32_bf16(wf, xf, acc[nt], 0, 0, 0);
        }
    }

    int row = m0 + wv * 16 + l15;
    if (row < M) {
        if (set == 0 || set == 3) {
            u16* Orow = (set == 0 ? Oq : Osk) + (size_t)row * 128;
#pragma unroll
            for (int nt = 0; nt < 8; ++nt) {
                uint2 pk;
                pk.x = pack2(acc[nt][0] + b4[nt][0], acc[nt][1] + b4[nt][1]);
                pk.y = pack2(acc[nt][2] + b4[nt][2], acc[nt][3] + b4[nt][3]);
                *reinterpret_cast<uint2*>(Orow + nt * 16 + quad * 4) = pk;
            }
        } else {
            u16* Orow = KVo + (size_t)row * 256 + (set == 2 ? 1 : 0);
#pragma unroll
            for (int nt = 0; nt < 8; ++nt) {
                int col0 = nt * 16 + quad * 4;
#pragma unroll
                for (int r = 0; r < 4; ++r)
                    Orow[(col0 + r) * 2] = f2bf(acc[nt][r] + b4[nt][r]);
            }
        }
    }
}

// ---------------- ee GEMM in CSR order, dual-layer, swapped + uint2 ---------
__global__ __launch_bounds__(256) void gemm_ee(
    const int* __restrict__ eids, const void* __restrict__ EF,
    const u16* __restrict__ WtE1 /*[128][32]*/, const u16* __restrict__ WtE2,
    const int* __restrict__ flags,
    u16* __restrict__ EE1, u16* __restrict__ EE2, int Etot) {
    constexpr int PAD = 40;
    __shared__ u16 Asl[64 * PAD];
    __shared__ u16 Bsl[2][128 * PAD];
    int p0 = blockIdx.x * 64;
    int f = flags[0];
    bool dual = (EE2 != nullptr);

    {
        int r = threadIdx.x >> 2, seg = threadIdx.x & 3;
        int p = p0 + r;
        int e = (p < Etot) ? eids[p] : 0;
        uint4 val;
        if (f) {
            const float* src = (const float*)EF + (size_t)e * 32 + seg * 8;
            float4 lo = *reinterpret_cast<const float4*>(src);
            float4 hi = *reinterpret_cast<const float4*>(src + 4);
            val = make_uint4(pack2(lo.x, lo.y), pack2(lo.z, lo.w),
                             pack2(hi.x, hi.y), pack2(hi.z, hi.w));
        } else {
            val = *reinterpret_cast<const uint4*>((const u16*)EF + (size_t)e * 32 + seg * 8);
        }
        *reinterpret_cast<uint4*>(&Asl[r * PAD + seg * 8]) = val;
    }
    for (int idx = threadIdx.x; idx < 128 * 4; idx += 256) {
        int r = idx >> 2, seg = idx & 3;
        *reinterpret_cast<uint4*>(&Bsl[0][r * PAD + seg * 8]) =
            *reinterpret_cast<const uint4*>(WtE1 + r * 32 + seg * 8);
    }
    if (dual) {
        for (int idx = threadIdx.x; idx < 128 * 4; idx += 256) {
            int r = idx >> 2, seg = idx & 3;
            *reinterpret_cast<uint4*>(&Bsl[1][r * PAD + seg * 8]) =
                *reinterpret_cast<const uint4*>(WtE2 + r * 32 + seg * 8);
        }
    }
    __syncthreads();

    int lane = threadIdx.x & 63, wv = threadIdx.x >> 6;
    int l15 = lane & 15;
    int quad = lane >> 4;
    int kq = quad * 8;
    int pos = p0 + wv * 16 + l15;
    bool ok = pos < Etot;
    bf16x8 ef8 = *reinterpret_cast<const bf16x8*>(&Asl[(wv * 16 + l15) * PAD + kq]);

    {
        f32x4 acc[8] = {};
#pragma unroll
        for (int nt = 0; nt < 8; ++nt) {
            bf16x8 wf = *reinterpret_cast<const bf16x8*>(&Bsl[0][(nt * 16 + l15) * PAD + kq]);
            acc[nt] = __builtin_amdgcn_mfma_f32_16x16x32_bf16(wf, ef8, acc[nt], 0, 0, 0);
        }
        if (ok) {
            u16* Orow = EE1 + (size_t)pos * 128;
#pragma unroll
            for (int nt = 0; nt < 8; ++nt) {
                uint2 pk;
                pk.x = pack2(acc[nt][0], acc[nt][1]);
                pk.y = pack2(acc[nt][2], acc[nt][3]);
                *reinterpret_cast<uint2*>(Orow + nt * 16 + quad * 4) = pk;
            }
        }
    }
    if (dual) {
        f32x4 acc[8] = {};
#pragma unroll
        for (int nt = 0; nt < 8; ++nt) {
            bf16x8 wf = *reinterpret_cast<const bf16x8*>(&Bsl[1][(nt * 16 + l15) * PAD + kq]);
            acc[nt] = __builtin_amdgcn_mfma_f32_16x16x32_bf16(wf, ef8, acc[nt], 0, 0, 0);
        }
        if (ok) {
            u16* Orow = EE2 + (size_t)pos * 128;
#pragma unroll
            for (int nt = 0; nt < 8; ++nt) {
                uint2 pk;
                pk.x = pack2(acc[nt][0], acc[nt][1]);
                pk.y = pack2(acc[nt][2], acc[nt][3]);
                *reinterpret_cast<uint2*>(Orow + nt * 16 + quad * 4) = pk;
            }
        }
    }
}

// ---------------- attention: exp (no max), DPP, interleaved kv --------------
// kv[node][col][0]=k, [1]=v -> one uint2 gather per edge per lane.
template <int HEADS, int F32OUT>
__global__ __launch_bounds__(256) void attn_kernel(
    const int* __restrict__ row_ptr, const int* __restrict__ srcs,
    const u16* __restrict__ Q, const u16* __restrict__ KVn,
    const u16* __restrict__ EE, const u16* __restrict__ SK,
    void* __restrict__ OUT, int nn) {
    int wv = threadIdx.x >> 6, lane = threadIdx.x & 63;
    int node = blockIdx.x * 4 + wv;
    if (node >= nn) return;
    int c0 = lane * 2;

    u32 qb = *reinterpret_cast<const u32*>(Q + (size_t)node * 128 + c0);
    float q0 = bflo(qb), q1 = bfhi(qb);

    int beg = row_ptr[node], end = row_ptr[node + 1];
    const float scale = (HEADS == 8) ? 0.25f : 0.08838834764831845f;  // 1/sqrt(C)
    constexpr int GRP = (HEADS == 8) ? 8 : 64;

    float l_run = 0.f, a0 = 0.f, a1 = 0.f;

    auto edge_step = [&](uint2 kvv, u32 ebv) {
        float e0 = bflo(ebv), e1 = bfhi(ebv);
        float k0 = bflo(kvv.x) + e0, k1 = bflo(kvv.y) + e1;
        float p = q0 * k0 + q1 * k1;
        p = grp_sum<GRP>(p, lane);
        float w = __expf(p * scale);
        l_run += w;
        a0 = fmaf(w, bfhi(kvv.x) + e0, a0);
        a1 = fmaf(w, bfhi(kvv.y) + e1, a1);
    };

    int i = beg;
    for (; i + 8 <= end; i += 8) {
        int sA[8];
#pragma unroll
        for (int j = 0; j < 8; ++j) sA[j] = srcs[i + j];
        uint2 kv2[8]; u32 eb[8];
#pragma unroll
        for (int j = 0; j < 8; ++j) {
            kv2[j] = *reinterpret_cast<const uint2*>(KVn + (size_t)sA[j] * 256 + c0 * 2);
            eb[j] = *reinterpret_cast<const u32*>(EE + (size_t)(i + j) * 128 + c0);
        }
#pragma unroll
        for (int j = 0; j < 8; ++j) edge_step(kv2[j], eb[j]);
    }
    for (; i < end; ++i) {
        int s = srcs[i];
        uint2 kvv = *reinterpret_cast<const uint2*>(KVn + (size_t)s * 256 + c0 * 2);
        u32 ebv = *reinterpret_cast<const u32*>(EE + (size_t)i * 128 + c0);
        edge_step(kvv, ebv);
    }

    float inv = 1.f / fmaxf(l_run, 1e-16f);
    u32 sb = *reinterpret_cast<const u32*>(SK + (size_t)node * 128 + c0);
    float o0 = fmaxf(a0 * inv + bflo(sb), 0.f);
    float o1 = fmaxf(a1 * inv + bfhi(sb), 0.f);
    if (F32OUT) {
        *reinterpret_cast<float2*>((float*)OUT + (size_t)node * 128 + c0) = make_float2(o0, o1);
    } else {
        *reinterpret_cast<u32*>((u16*)OUT + (size_t)node * 128 + c0) = pack2(o0, o1);
    }
}

// ---------------- fallback attention (no materialized ee) -------------------
template <int HEADS, int F32OUT>
__global__ __launch_bounds__(256) void attn_fused(
    const int* __restrict__ row_ptr, const int* __restrict__ srcs,
    const int* __restrict__ eids, const int* __restrict__ flags,
    const u16* __restrict__ Q, const u16* __restrict__ KVn,
    const void* __restrict__ EF, const void* __restrict__ We,
    const u16* __restrict__ SK, void* __restrict__ OUT, int nn) {
    int wv = threadIdx.x >> 6, lane = threadIdx.x & 63;
    int node = blockIdx.x * 4 + wv;
    if (node >= nn) return;
    int c0 = lane * 2;
    int f = flags[0];

    float wf0[32], wf1[32];
    if (f) {
        const float* Wef = (const float*)We;
#pragma unroll
        for (int d = 0; d < 32; ++d) {
            float2 w2 = *reinterpret_cast<const float2*>(Wef + d * 128 + c0);
            wf0[d] = w2.x; wf1[d] = w2.y;
        }
    } else {
        const u16* Web = (const u16*)We;
#pragma unroll
        for (int d = 0; d < 32; ++d) {
            u32 w = *reinterpret_cast<const u32*>(Web + d * 128 + c0);
            wf0[d] = bflo(w); wf1[d] = bfhi(w);
        }
    }

    u32 qb = *reinterpret_cast<const u32*>(Q + (size_t)node * 128 + c0);
    float q0 = bflo(qb), q1 = bfhi(qb);
    int beg = row_ptr[node], end = row_ptr[node + 1];
    const float scale = (HEADS == 8) ? 0.25f : 0.08838834764831845f;
    constexpr int GRP = (HEADS == 8) ? 8 : 64;
    float l_run = 0.f, a0 = 0.f, a1 = 0.f;

    for (int i = beg; i < end; ++i) {
        int s = srcs[i], e = eids[i];
        uint2 kvv = *reinterpret_cast<const uint2*>(KVn + (size_t)s * 256 + c0 * 2);
        float efv[32];
        if (f) {
            const float* eff = (const float*)EF + (size_t)e * 32;
#pragma unroll
            for (int t = 0; t < 8; ++t) {
                float4 q4 = *reinterpret_cast<const float4*>(eff + t * 4);
                efv[4 * t] = q4.x; efv[4 * t + 1] = q4.y;
                efv[4 * t + 2] = q4.z; efv[4 * t + 3] = q4.w;
            }
        } else {
            const uint4* efp = reinterpret_cast<const uint4*>((const u16*)EF + (size_t)e * 32);
            uint4 ea = efp[0], eb2 = efp[1], ec = efp[2], ed = efp[3];
            u32 efw[16] = {ea.x, ea.y, ea.z, ea.w, eb2.x, eb2.y, eb2.z, eb2.w,
                           ec.x, ec.y, ec.z, ec.w, ed.x, ed.y, ed.z, ed.w};
#pragma unroll
            for (int t = 0; t < 16; ++t) {
                efv[2 * t] = bflo(efw[t]);
                efv[2 * t + 1] = bfhi(efw[t]);
            }
        }
        float ee0 = 0.f, ee1 = 0.f;
#pragma unroll
        for (int t = 0; t < 32; ++t) {
            ee0 = fmaf(efv[t], wf0[t], ee0);
            ee1 = fmaf(efv[t], wf1[t], ee1);
        }
        float k0 = bflo(kvv.x) + ee0, k1 = bflo(kvv.y) + ee1;
        float p = q0 * k0 + q1 * k1;
        p = grp_sum<GRP>(p, lane);
        float w = __expf(p * scale);
        l_run += w;
        a0 = fmaf(w, bfhi(kvv.x) + ee0, a0);
        a1 = fmaf(w, bfhi(kvv.y) + ee1, a1);
    }

    float inv = 1.f / fmaxf(l_run, 1e-16f);
    u32 sb = *reinterpret_cast<const u32*>(SK + (size_t)node * 128 + c0);
    float o0 = fmaxf(a0 * inv + bflo(sb), 0.f);
    float o1 = fmaxf(a1 * inv + bfhi(sb), 0.f);
    if (F32OUT) {
        *reinterpret_cast<float2*>((float*)OUT + (size_t)node * 128 + c0) = make_float2(o0, o1);
    } else {
        *reinterpret_cast<u32*>((u16*)OUT + (size_t)node * 128 + c0) = pack2(o0, o1);
    }
}

// ---------------------------------------------------------------------------
extern "C" void kernel_launch(void* const* d_in, const int* in_sizes, int n_in,
                              void* d_out, int out_size, void* d_ws, size_t ws_size,
                              hipStream_t stream) {
    const int N = NODES, E = EDGES;
    const void* x  = d_in[0];
    const int*  ei = (const int*)d_in[1];
    const void* ef = d_in[2];
    const void* Wq1 = d_in[3];  const void* bq1 = d_in[4];
    const void* Wk1 = d_in[5];  const void* bk1 = d_in[6];
    const void* Wv1 = d_in[7];  const void* bv1 = d_in[8];
    const void* We1 = d_in[9];
    const void* Ws1 = d_in[10]; const void* bs1 = d_in[11];
    const void* Wq2 = d_in[12]; const void* bq2 = d_in[13];
    const void* Wk2 = d_in[14]; const void* bk2 = d_in[15];
    const void* Wv2 = d_in[16]; const void* bv2 = d_in[17];
    const void* We2 = d_in[18];
    const void* Ws2 = d_in[19]; const void* bs2 = d_in[20];

    char* ws = (char*)d_ws;
    size_t off = 0;
    auto carve = [&](size_t bytes) -> void* {
        void* p = ws + off;
        off += (bytes + 255) & ~(size_t)255;
        return p;
    };

    u16* WtQ1 = (u16*)carve(128 * 128 * 2);
    u16* WtK1 = (u16*)carve(128 * 128 * 2);
    u16* WtV1 = (u16*)carve(128 * 128 * 2);
    u16* WtS1 = (u16*)carve(128 * 128 * 2);
    u16* WtQ2 = (u16*)carve(128 * 128 * 2);
    u16* WtK2 = (u16*)carve(128 * 128 * 2);
    u16* WtV2 = (u16*)carve(128 * 128 * 2);
    u16* WtS2 = (u16*)carve(128 * 128 * 2);
    u16* WtE1 = (u16*)carve(128 * 32 * 2);
    u16* WtE2 = (u16*)carve(128 * 32 * 2);
    int* flags   = (int*)carve(256);
    int* deg     = (int*)carve((size_t)N * 4);
    int* bsum    = (int*)carve((size_t)NB196 * 4);
    int* row_ptr = (int*)carve((size_t)(N + 1) * 4);
    int* cursor  = (int*)carve((size_t)N * 4);
    int* srcs    = (int*)carve((size_t)E * 4);
    int* eids    = (int*)carve((size_t)E * 4);
    u16* q  = (u16*)carve((size_t)N * 128 * 2);
    u16* kv = (u16*)carve((size_t)N * 256 * 2);   // interleaved k/v
    u16* sk = (u16*)carve((size_t)N * 128 * 2);
    u16* h  = (u16*)carve((size_t)N * 128 * 2);
    const size_t REQ_BASE = off;                        // ~68 MB
    u16* ee1 = (u16*)carve((size_t)E * 128 * 2);        // +102.4 MB
    const size_t REQ_BIG = off;                         // ~171 MB (fit R7-R12)
    u16* ee2 = (u16*)carve((size_t)E * 128 * 2);        // +102.4 MB
    const size_t REQ_2EE = off;                         // ~273 MB
    const bool DUAL  = (ws_size >= REQ_2EE);
    const bool MATOK = (ws_size >= REQ_BIG);

    if (ws_size < REQ_BASE) {
        hipLaunchKernelGGL(fill_sentinel, dim3((out_size + 255) / 256), dim3(256), 0, stream,
                           (float*)d_out, out_size, 16.0f * (float)(ws_size >> 20));
        return;
    }

    hipLaunchKernelGGL(detect_fmt, dim3(1), dim3(64), 0, stream, (const u32*)x, ei, flags);

    TPtrs tp;
    tp.src[0] = Wq1; tp.dst[0] = WtQ1; tp.K[0] = 128;
    tp.src[1] = Wk1; tp.dst[1] = WtK1; tp.K[1] = 128;
    tp.src[2] = Wv1; tp.dst[2] = WtV1; tp.K[2] = 128;
    tp.src[3] = Ws1; tp.dst[3] = WtS1; tp.K[3] = 128;
    tp.src[4] = Wq2; tp.dst[4] = WtQ2; tp.K[4] = 128;
    tp.src[5] = Wk2; tp.dst[5] = WtK2; tp.K[5] = 128;
    tp.src[6] = Wv2; tp.dst[6] = WtV2; tp.K[6] = 128;
    tp.src[7] = Ws2; tp.dst[7] = WtS2; tp.K[7] = 128;
    tp.src[8] = We1; tp.dst[8] = WtE1; tp.K[8] = 32;
    tp.src[9] = We2; tp.dst[9] = WtE2; tp.K[9] = 32;
    hipLaunchKernelGGL(transpose_w, dim3(10, 4), dim3(256), 0, stream, tp, flags);

    (void)hipMemsetAsync(deg, 0, (size_t)N * 4, stream);
    hipLaunchKernelGGL(count_deg, dim3((E + 255) / 256), dim3(256), 0, stream, ei, flags, deg, E);
    hipLaunchKernelGGL(scan_a, dim3(NB196), dim3(256), 0, stream, deg, bsum, N);
    hipLaunchKernelGGL(scan_b, dim3(1), dim3(256), 0, stream, bsum, NB196);
    hipLaunchKernelGGL(scan_c, dim3(NB196), dim3(256), 0, stream, deg, bsum, row_ptr, cursor, N);
    hipLaunchKernelGGL(fill_csr, dim3((E + 255) / 256), dim3(256), 0, stream, ei, flags, cursor,
                       srcs, eids, E);

    const int gN = (N + 63) / 64;   // 782
    const int gE = E / 64;          // 6250
    const int gA = (N + 3) / 4;     // 12500

    if (MATOK) {
        hipLaunchKernelGGL(gemm_ee, dim3(gE), dim3(256), 0, stream,
                           eids, ef, WtE1, WtE2, flags,
                           ee1, DUAL ? ee2 : (u16*)nullptr, E);
    }

    // layer 1
    hipLaunchKernelGGL(gemm128, dim3(gN, 4), dim3(256), 0, stream,
                       x, flags, 1, WtQ1, WtK1, WtV1, WtS1,
                       bq1, bk1, bv1, bs1, q, kv, sk, N);
    if (MATOK) {
        hipLaunchKernelGGL((attn_kernel<8, 0>), dim3(gA), dim3(256), 0, stream,
                           row_ptr, srcs, q, kv, ee1, sk, (void*)h, N);
    } else {
        hipLaunchKernelGGL((attn_fused<8, 0>), dim3(gA), dim3(256), 0, stream,
                           row_ptr, srcs, eids, flags, q, kv, ef, We1, sk, (void*)h, N);
    }

    // layer 2
    hipLaunchKernelGGL(gemm128, dim3(gN, 4), dim3(256), 0, stream,
                       h, flags, 0, WtQ2, WtK2, WtV2, WtS2,
                       bq2, bk2, bv2, bs2, q, kv, sk, N);
    if (MATOK) {
        if (!DUAL) {
            hipLaunchKernelGGL(gemm_ee, dim3(gE), dim3(256), 0, stream,
                               eids, ef, WtE2, (const u16*)nullptr, flags,
                               ee1, (u16*)nullptr, E);
        }
        hipLaunchKernelGGL((attn_kernel<1, 1>), dim3(gA), dim3(256), 0, stream,
                           row_ptr, srcs, q, kv, DUAL ? ee2 : ee1, sk, d_out, N);
    } else {
        hipLaunchKernelGGL((attn_fused<1, 1>), dim3(gA), dim3(256), 0, stream,
                           row_ptr, srcs, eids, flags, q, kv, ef, We2, sk, d_out, N);
    }
}

// Round 14
// 459.900 us; speedup vs baseline: 1.0721x; 1.0721x over previous
//
#include <hip/hip_runtime.h>

// GraphAttentionEmbedding: 2x TransformerConv (PyG) on MI355X (gfx950).
// N=50000, E=400000, IN=128, H1=8*16=128, OUT=128, EDIM=32.
// PROVEN: fp32 inputs (runtime-detected), fp32 output; internal bf16+fp32 acc.
// GEMM lessons: LDS-staged A+B, one weight set/block = fast (R7-R10).
// R13 lesson: k/v interleaved stride-2 stores = +50% WRITE_SIZE (RMW) - revert.
// R14: operand-swapped MFMA uint2 epilogue for ALL sets (verified R13),
// x pre-converted to bf16 once (halves gemm A-fetch), R12 attn unchanged.

using u16 = unsigned short;
using u32 = unsigned int;

#define NODES 50000
#define EDGES 400000
#define NB196 196   // ceil(50000/256)

typedef __attribute__((ext_vector_type(8))) short bf16x8;
typedef __attribute__((ext_vector_type(4))) float f32x4;

__device__ __forceinline__ float bflo(u32 u) { return __uint_as_float(u << 16); }
__device__ __forceinline__ float bfhi(u32 u) { return __uint_as_float(u & 0xffff0000u); }
__device__ __forceinline__ u16 f2bf(float f) {
    u32 u = __float_as_uint(f);
    u += 0x7fffu + ((u >> 16) & 1u);   // RNE
    return (u16)(u >> 16);
}
__device__ __forceinline__ u32 pack2(float a, float b) {
    return (u32)f2bf(a) | ((u32)f2bf(b) << 16);
}

// DPP lane-add at VALU speed (no DS pipe).
template <int CTRL>
__device__ __forceinline__ float dpp_addf(float x) {
    int y = __builtin_amdgcn_update_dpp(0, __float_as_int(x), CTRL, 0xF, 0xF, true);
    return x + __int_as_float(y);
}
template <int GRP>
__device__ __forceinline__ float grp_sum(float p, int lane) {
    p = dpp_addf<0xB1>(p);    // xor 1
    p = dpp_addf<0x4E>(p);    // xor 2
    p = dpp_addf<0x141>(p);   // xor 4 (8-group done)
    if (GRP == 64) {
        p = dpp_addf<0x140>(p);   // xor 8
        p += __int_as_float(__builtin_amdgcn_ds_swizzle(__float_as_int(p), 0x401F)); // xor16
        p += __int_as_float(__builtin_amdgcn_ds_bpermute((lane ^ 32) << 2,
                                                         __float_as_int(p)));        // xor32
    }
    return p;
}

// ---------------- diagnostic sentinel (fp32 out) ----------------------------
__global__ __launch_bounds__(256) void fill_sentinel(float* __restrict__ out, int n, float val) {
    int i = blockIdx.x * 256 + threadIdx.x;
    if (i < n) out[i] = val;
}

// ---------------- runtime format detection (one wave) -----------------------
__global__ __launch_bounds__(64) void detect_fmt(const u32* __restrict__ xw,
                                                 const int* __restrict__ eraw,
                                                 int* __restrict__ flags) {
    int lane = threadIdx.x;
    u32 e = (xw[lane] >> 7) & 0xffu;
    unsigned long long sane = __ballot(e >= 90u && e <= 141u);
    unsigned long long zodd = __ballot(eraw[1 + 2 * lane] == 0);
    if (lane == 0) {
        flags[0] = (sane == ~0ull) ? 0 : 1;   // 1 = fp32
        flags[1] = (zodd == ~0ull) ? 1 : 0;   // 1 = int64
    }
}

// ---------------- x -> bf16 conversion (once) -------------------------------
__global__ __launch_bounds__(256) void convert_x(const void* __restrict__ X,
                                                 const int* __restrict__ flags,
                                                 u16* __restrict__ xbf, int total) {
    int i = (blockIdx.x * 256 + threadIdx.x) * 8;
    if (i >= total) return;
    if (flags[0]) {
        const float* xf = (const float*)X + i;
        float4 lo = *reinterpret_cast<const float4*>(xf);
        float4 hi = *reinterpret_cast<const float4*>(xf + 4);
        uint4 val = make_uint4(pack2(lo.x, lo.y), pack2(lo.z, lo.w),
                               pack2(hi.x, hi.y), pack2(hi.z, hi.w));
        *reinterpret_cast<uint4*>(xbf + i) = val;
    } else {
        *reinterpret_cast<uint4*>(xbf + i) =
            *reinterpret_cast<const uint4*>((const u16*)X + i);
    }
}

// ---------------- weight transpose+convert: W[K][128] -> Wt[128][K] bf16 ----
struct TPtrs {
    const void* src[10];
    u16*        dst[10];
    int         K[10];
};

__global__ __launch_bounds__(256) void transpose_w(TPtrs P, const int* __restrict__ fmt) {
    int m = blockIdx.x;
    int f = *fmt;
    int K = P.K[m];
    int quarter = (K * 128) >> 2;
    u16* d = P.dst[m];
    int base = blockIdx.y * quarter;
    const float* sf = (const float*)P.src[m];
    const u16*   sb = (const u16*)P.src[m];
    for (int idx = base + threadIdx.x; idx < base + quarter; idx += 256) {
        int k = idx >> 7, n = idx & 127;
        d[n * K + k] = f ? f2bf(sf[idx]) : sb[idx];
    }
}

// ---------------- CSR build (by dst) ----------------------------------------
__global__ __launch_bounds__(256) void count_deg(const int* __restrict__ raw,
                                                 const int* __restrict__ flags,
                                                 int* __restrict__ deg, int E) {
    int e = blockIdx.x * 256 + threadIdx.x;
    if (e < E) {
        int f = flags[1];
        int d = f ? raw[2 * (E + e)] : raw[E + e];
        if ((unsigned)d < (unsigned)NODES) atomicAdd(&deg[d], 1);
    }
}

__device__ __forceinline__ int block_scan256(int v) {
    __shared__ int ws[4];
    int t = threadIdx.x, lane = t & 63, w = t >> 6;
    int x = v;
#pragma unroll
    for (int off = 1; off < 64; off <<= 1) {
        int y = __shfl_up(x, off, 64);
        if (lane >= off) x += y;
    }
    if (lane == 63) ws[w] = x;
    __syncthreads();
#pragma unroll
    for (int j = 0; j < 3; ++j)
        if (j < w) x += ws[j];
    return x;
}

__global__ __launch_bounds__(256) void scan_a(const int* __restrict__ deg,
                                              int* __restrict__ bsum, int n) {
    int i = blockIdx.x * 256 + threadIdx.x;
    int v = (i < n) ? deg[i] : 0;
    int incl = block_scan256(v);
    if (threadIdx.x == 255) bsum[blockIdx.x] = incl;
}

__global__ __launch_bounds__(256) void scan_b(int* __restrict__ bsum, int nb) {
    int t = threadIdx.x;
    int v = (t < nb) ? bsum[t] : 0;
    int incl = block_scan256(v);
    if (t < nb) bsum[t] = incl - v;
}

__global__ __launch_bounds__(256) void scan_c(const int* __restrict__ deg,
                                              const int* __restrict__ bsum,
                                              int* __restrict__ row_ptr,
                                              int* __restrict__ cursor, int n) {
    int b = blockIdx.x;
    int i = b * 256 + threadIdx.x;
    int v = (i < n) ? deg[i] : 0;
    int incl = block_scan256(v) + bsum[b];
    if (i < n) {
        row_ptr[i + 1] = incl;
        cursor[i] = incl - v;
    }
    if (i == 0) row_ptr[0] = 0;
}

__global__ __launch_bounds__(256) void fill_csr(const int* __restrict__ raw,
                                                const int* __restrict__ flags,
                                                int* __restrict__ cursor,
                                                int* __restrict__ srcs,
                                                int* __restrict__ eids, int E) {
    int e = blockIdx.x * 256 + threadIdx.x;
    if (e < E) {
        int f = flags[1];
        int d = f ? raw[2 * (E + e)] : raw[E + e];
        int s = f ? raw[2 * e] : raw[e];
        if ((unsigned)d < (unsigned)NODES && (unsigned)s < (unsigned)NODES) {
            int pos = atomicAdd(&cursor[d], 1);
            if ((unsigned)pos < (unsigned)E) { srcs[pos] = s; eids[pos] = e; }
        }
    }
}

// ---------------- GEMM: O[M,128] = A[M,128] @ Wt[128,128]^T + bias ----------
// LDS-staged A (bf16, pre-converted) + B; one weight set per block (grid y=4).
// Operand-swapped MFMA: lane acc[nt] = 4 consecutive out-cols of one row
// -> epilogue is 8 coalesced uint2 stores (verified correct in R13).
__global__ __launch_bounds__(256) void gemm128(
    const u16* __restrict__ A, const int* __restrict__ flags,
    const u16* __restrict__ Wt0, const u16* __restrict__ Wt1,
    const u16* __restrict__ Wt2, const u16* __restrict__ Wt3,
    const void* __restrict__ b0, const void* __restrict__ b1,
    const void* __restrict__ b2, const void* __restrict__ b3,
    u16* __restrict__ O0, u16* __restrict__ O1,
    u16* __restrict__ O2, u16* __restrict__ O3,
    int M) {
    constexpr int K = 128;
    constexpr int PAD = K + 8;
    constexpr int KV = K / 8;
    __shared__ u16 Asl[64 * PAD];
    __shared__ u16 Bsl[128 * PAD];

    int f = flags[0];
    const u16* Wt; const void* bias; u16* O;
    switch (blockIdx.y) {
        case 0: Wt = Wt0; bias = b0; O = O0; break;
        case 1: Wt = Wt1; bias = b1; O = O1; break;
        case 2: Wt = Wt2; bias = b2; O = O2; break;
        default: Wt = Wt3; bias = b3; O = O3; break;
    }
    int m0 = blockIdx.x * 64;

    for (int idx = threadIdx.x; idx < 64 * KV; idx += 256) {
        int r = idx / KV, cv = idx % KV;
        int gr = m0 + r;
        uint4 val = make_uint4(0, 0, 0, 0);
        if (gr < M) val = *reinterpret_cast<const uint4*>(A + (size_t)gr * K + cv * 8);
        *reinterpret_cast<uint4*>(&Asl[r * PAD + cv * 8]) = val;
    }
    for (int idx = threadIdx.x; idx < 128 * KV; idx += 256) {
        int r = idx / KV, cv = idx % KV;
        *reinterpret_cast<uint4*>(&Bsl[r * PAD + cv * 8]) =
            *reinterpret_cast<const uint4*>(Wt + r * K + cv * 8);
    }
    __syncthreads();

    int lane = threadIdx.x & 63, wv = threadIdx.x >> 6;
    int l15 = lane & 15;
    int quad = lane >> 4;
    int kq = quad * 8;

    f32x4 b4[8];
#pragma unroll
    for (int nt = 0; nt < 8; ++nt) {
        int col0 = nt * 16 + quad * 4;
        if (bias) {
            if (f) {
                b4[nt] = *reinterpret_cast<const f32x4*>((const float*)bias + col0);
            } else {
                uint2 bu = *reinterpret_cast<const uint2*>((const u16*)bias + col0);
                b4[nt][0] = bflo(bu.x); b4[nt][1] = bfhi(bu.x);
                b4[nt][2] = bflo(bu.y); b4[nt][3] = bfhi(bu.y);
            }
        } else {
            b4[nt][0] = b4[nt][1] = b4[nt][2] = b4[nt][3] = 0.f;
        }
    }

    f32x4 acc[8] = {};
#pragma unroll
    for (int k0 = 0; k0 < K; k0 += 32) {
        bf16x8 xf = *reinterpret_cast<const bf16x8*>(&Asl[(wv * 16 + l15) * PAD + k0 + kq]);
#pragma unroll
        for (int nt = 0; nt < 8; ++nt) {
            bf16x8 wf = *reinterpret_cast<const bf16x8*>(&Bsl[(nt * 16 + l15) * PAD + k0 + kq]);
            acc[nt] = __builtin_amdgcn_mfma_f32_16x16x32_bf16(wf, xf, acc[nt], 0, 0, 0);
        }
    }

    int row = m0 + wv * 16 + l15;
    if (row < M) {
        u16* Orow = O + (size_t)row * 128;
#pragma unroll
        for (int nt = 0; nt < 8; ++nt) {
            uint2 pk;
            pk.x = pack2(acc[nt][0] + b4[nt][0], acc[nt][1] + b4[nt][1]);
            pk.y = pack2(acc[nt][2] + b4[nt][2], acc[nt][3] + b4[nt][3]);
            *reinterpret_cast<uint2*>(Orow + nt * 16 + quad * 4) = pk;
        }
    }
}

// ---------------- ee GEMM in CSR order, dual-layer, swapped + uint2 ---------
__global__ __launch_bounds__(256) void gemm_ee(
    const int* __restrict__ eids, const void* __restrict__ EF,
    const u16* __restrict__ WtE1 /*[128][32]*/, const u16* __restrict__ WtE2,
    const int* __restrict__ flags,
    u16* __restrict__ EE1, u16* __restrict__ EE2, int Etot) {
    constexpr int PAD = 40;
    __shared__ u16 Asl[64 * PAD];
    __shared__ u16 Bsl[2][128 * PAD];
    int p0 = blockIdx.x * 64;
    int f = flags[0];
    bool dual = (EE2 != nullptr);

    {
        int r = threadIdx.x >> 2, seg = threadIdx.x & 3;
        int p = p0 + r;
        int e = (p < Etot) ? eids[p] : 0;
        uint4 val;
        if (f) {
            const float* src = (const float*)EF + (size_t)e * 32 + seg * 8;
            float4 lo = *reinterpret_cast<const float4*>(src);
            float4 hi = *reinterpret_cast<const float4*>(src + 4);
            val = make_uint4(pack2(lo.x, lo.y), pack2(lo.z, lo.w),
                             pack2(hi.x, hi.y), pack2(hi.z, hi.w));
        } else {
            val = *reinterpret_cast<const uint4*>((const u16*)EF + (size_t)e * 32 + seg * 8);
        }
        *reinterpret_cast<uint4*>(&Asl[r * PAD + seg * 8]) = val;
    }
    for (int idx = threadIdx.x; idx < 128 * 4; idx += 256) {
        int r = idx >> 2, seg = idx & 3;
        *reinterpret_cast<uint4*>(&Bsl[0][r * PAD + seg * 8]) =
            *reinterpret_cast<const uint4*>(WtE1 + r * 32 + seg * 8);
    }
    if (dual) {
        for (int idx = threadIdx.x; idx < 128 * 4; idx += 256) {
            int r = idx >> 2, seg = idx & 3;
            *reinterpret_cast<uint4*>(&Bsl[1][r * PAD + seg * 8]) =
                *reinterpret_cast<const uint4*>(WtE2 + r * 32 + seg * 8);
        }
    }
    __syncthreads();

    int lane = threadIdx.x & 63, wv = threadIdx.x >> 6;
    int l15 = lane & 15;
    int quad = lane >> 4;
    int kq = quad * 8;
    int pos = p0 + wv * 16 + l15;
    bool ok = pos < Etot;
    bf16x8 ef8 = *reinterpret_cast<const bf16x8*>(&Asl[(wv * 16 + l15) * PAD + kq]);

    {
        f32x4 acc[8] = {};
#pragma unroll
        for (int nt = 0; nt < 8; ++nt) {
            bf16x8 wf = *reinterpret_cast<const bf16x8*>(&Bsl[0][(nt * 16 + l15) * PAD + kq]);
            acc[nt] = __builtin_amdgcn_mfma_f32_16x16x32_bf16(wf, ef8, acc[nt], 0, 0, 0);
        }
        if (ok) {
            u16* Orow = EE1 + (size_t)pos * 128;
#pragma unroll
            for (int nt = 0; nt < 8; ++nt) {
                uint2 pk;
                pk.x = pack2(acc[nt][0], acc[nt][1]);
                pk.y = pack2(acc[nt][2], acc[nt][3]);
                *reinterpret_cast<uint2*>(Orow + nt * 16 + quad * 4) = pk;
            }
        }
    }
    if (dual) {
        f32x4 acc[8] = {};
#pragma unroll
        for (int nt = 0; nt < 8; ++nt) {
            bf16x8 wf = *reinterpret_cast<const bf16x8*>(&Bsl[1][(nt * 16 + l15) * PAD + kq]);
            acc[nt] = __builtin_amdgcn_mfma_f32_16x16x32_bf16(wf, ef8, acc[nt], 0, 0, 0);
        }
        if (ok) {
            u16* Orow = EE2 + (size_t)pos * 128;
#pragma unroll
            for (int nt = 0; nt < 8; ++nt) {
                uint2 pk;
                pk.x = pack2(acc[nt][0], acc[nt][1]);
                pk.y = pack2(acc[nt][2], acc[nt][3]);
                *reinterpret_cast<uint2*>(Orow + nt * 16 + quad * 4) = pk;
            }
        }
    }
}

// ---------------- attention: exp (no max), DPP, 8-batches (R12 form) --------
template <int HEADS, int F32OUT>
__global__ __launch_bounds__(256) void attn_kernel(
    const int* __restrict__ row_ptr, const int* __restrict__ srcs,
    const u16* __restrict__ Q, const u16* __restrict__ Kn,
    const u16* __restrict__ Vn, const u16* __restrict__ EE,
    const u16* __restrict__ SK, void* __restrict__ OUT, int nn) {
    int wv = threadIdx.x >> 6, lane = threadIdx.x & 63;
    int node = blockIdx.x * 4 + wv;
    if (node >= nn) return;
    int c0 = lane * 2;

    u32 qb = *reinterpret_cast<const u32*>(Q + (size_t)node * 128 + c0);
    float q0 = bflo(qb), q1 = bfhi(qb);

    int beg = row_ptr[node], end = row_ptr[node + 1];
    const float scale = (HEADS == 8) ? 0.25f : 0.08838834764831845f;  // 1/sqrt(C)
    constexpr int GRP = (HEADS == 8) ? 8 : 64;

    float l_run = 0.f, a0 = 0.f, a1 = 0.f;

    auto edge_step = [&](u32 kbv, u32 vbv, u32 ebv) {
        float e0 = bflo(ebv), e1 = bfhi(ebv);
        float k0 = bflo(kbv) + e0, k1 = bfhi(kbv) + e1;
        float p = q0 * k0 + q1 * k1;
        p = grp_sum<GRP>(p, lane);
        float w = __expf(p * scale);
        l_run += w;
        a0 = fmaf(w, bflo(vbv) + e0, a0);
        a1 = fmaf(w, bfhi(vbv) + e1, a1);
    };

    int i = beg;
    for (; i + 8 <= end; i += 8) {
        int sA[8];
#pragma unroll
        for (int j = 0; j < 8; ++j) sA[j] = srcs[i + j];
        u32 kb[8], vb[8], eb[8];
#pragma unroll
        for (int j = 0; j < 8; ++j) {
            kb[j] = *reinterpret_cast<const u32*>(Kn + (size_t)sA[j] * 128 + c0);
            vb[j] = *reinterpret_cast<const u32*>(Vn + (size_t)sA[j] * 128 + c0);
            eb[j] = *reinterpret_cast<const u32*>(EE + (size_t)(i + j) * 128 + c0);
        }
#pragma unroll
        for (int j = 0; j < 8; ++j) edge_step(kb[j], vb[j], eb[j]);
    }
    for (; i < end; ++i) {
        int s = srcs[i];
        u32 kbv = *reinterpret_cast<const u32*>(Kn + (size_t)s * 128 + c0);
        u32 vbv = *reinterpret_cast<const u32*>(Vn + (size_t)s * 128 + c0);
        u32 ebv = *reinterpret_cast<const u32*>(EE + (size_t)i * 128 + c0);
        edge_step(kbv, vbv, ebv);
    }

    float inv = 1.f / fmaxf(l_run, 1e-16f);
    u32 sb = *reinterpret_cast<const u32*>(SK + (size_t)node * 128 + c0);
    float o0 = fmaxf(a0 * inv + bflo(sb), 0.f);
    float o1 = fmaxf(a1 * inv + bfhi(sb), 0.f);
    if (F32OUT) {
        *reinterpret_cast<float2*>((float*)OUT + (size_t)node * 128 + c0) = make_float2(o0, o1);
    } else {
        *reinterpret_cast<u32*>((u16*)OUT + (size_t)node * 128 + c0) = pack2(o0, o1);
    }
}

// ---------------- fallback attention (no materialized ee) -------------------
template <int HEADS, int F32OUT>
__global__ __launch_bounds__(256) void attn_fused(
    const int* __restrict__ row_ptr, const int* __restrict__ srcs,
    const int* __restrict__ eids, const int* __restrict__ flags,
    const u16* __restrict__ Q, const u16* __restrict__ Kn,
    const u16* __restrict__ Vn, const void* __restrict__ EF,
    const void* __restrict__ We, const u16* __restrict__ SK,
    void* __restrict__ OUT, int nn) {
    int wv = threadIdx.x >> 6, lane = threadIdx.x & 63;
    int node = blockIdx.x * 4 + wv;
    if (node >= nn) return;
    int c0 = lane * 2;
    int f = flags[0];

    float wf0[32], wf1[32];
    if (f) {
        const float* Wef = (const float*)We;
#pragma unroll
        for (int d = 0; d < 32; ++d) {
            float2 w2 = *reinterpret_cast<const float2*>(Wef + d * 128 + c0);
            wf0[d] = w2.x; wf1[d] = w2.y;
        }
    } else {
        const u16* Web = (const u16*)We;
#pragma unroll
        for (int d = 0; d < 32; ++d) {
            u32 w = *reinterpret_cast<const u32*>(Web + d * 128 + c0);
            wf0[d] = bflo(w); wf1[d] = bfhi(w);
        }
    }

    u32 qb = *reinterpret_cast<const u32*>(Q + (size_t)node * 128 + c0);
    float q0 = bflo(qb), q1 = bfhi(qb);
    int beg = row_ptr[node], end = row_ptr[node + 1];
    const float scale = (HEADS == 8) ? 0.25f : 0.08838834764831845f;
    constexpr int GRP = (HEADS == 8) ? 8 : 64;
    float l_run = 0.f, a0 = 0.f, a1 = 0.f;

    for (int i = beg; i < end; ++i) {
        int s = srcs[i], e = eids[i];
        u32 kbv = *reinterpret_cast<const u32*>(Kn + (size_t)s * 128 + c0);
        u32 vbv = *reinterpret_cast<const u32*>(Vn + (size_t)s * 128 + c0);
        float efv[32];
        if (f) {
            const float* eff = (const float*)EF + (size_t)e * 32;
#pragma unroll
            for (int t = 0; t < 8; ++t) {
                float4 q4 = *reinterpret_cast<const float4*>(eff + t * 4);
                efv[4 * t] = q4.x; efv[4 * t + 1] = q4.y;
                efv[4 * t + 2] = q4.z; efv[4 * t + 3] = q4.w;
            }
        } else {
            const uint4* efp = reinterpret_cast<const uint4*>((const u16*)EF + (size_t)e * 32);
            uint4 ea = efp[0], eb2 = efp[1], ec = efp[2], ed = efp[3];
            u32 efw[16] = {ea.x, ea.y, ea.z, ea.w, eb2.x, eb2.y, eb2.z, eb2.w,
                           ec.x, ec.y, ec.z, ec.w, ed.x, ed.y, ed.z, ed.w};
#pragma unroll
            for (int t = 0; t < 16; ++t) {
                efv[2 * t] = bflo(efw[t]);
                efv[2 * t + 1] = bfhi(efw[t]);
            }
        }
        float ee0 = 0.f, ee1 = 0.f;
#pragma unroll
        for (int t = 0; t < 32; ++t) {
            ee0 = fmaf(efv[t], wf0[t], ee0);
            ee1 = fmaf(efv[t], wf1[t], ee1);
        }
        float k0 = bflo(kbv) + ee0, k1 = bfhi(kbv) + ee1;
        float p = q0 * k0 + q1 * k1;
        p = grp_sum<GRP>(p, lane);
        float w = __expf(p * scale);
        l_run += w;
        a0 = fmaf(w, bflo(vbv) + ee0, a0);
        a1 = fmaf(w, bfhi(vbv) + ee1, a1);
    }

    float inv = 1.f / fmaxf(l_run, 1e-16f);
    u32 sb = *reinterpret_cast<const u32*>(SK + (size_t)node * 128 + c0);
    float o0 = fmaxf(a0 * inv + bflo(sb), 0.f);
    float o1 = fmaxf(a1 * inv + bfhi(sb), 0.f);
    if (F32OUT) {
        *reinterpret_cast<float2*>((float*)OUT + (size_t)node * 128 + c0) = make_float2(o0, o1);
    } else {
        *reinterpret_cast<u32*>((u16*)OUT + (size_t)node * 128 + c0) = pack2(o0, o1);
    }
}

// ---------------------------------------------------------------------------
extern "C" void kernel_launch(void* const* d_in, const int* in_sizes, int n_in,
                              void* d_out, int out_size, void* d_ws, size_t ws_size,
                              hipStream_t stream) {
    const int N = NODES, E = EDGES;
    const void* x  = d_in[0];
    const int*  ei = (const int*)d_in[1];
    const void* ef = d_in[2];
    const void* Wq1 = d_in[3];  const void* bq1 = d_in[4];
    const void* Wk1 = d_in[5];  const void* bk1 = d_in[6];
    const void* Wv1 = d_in[7];  const void* bv1 = d_in[8];
    const void* We1 = d_in[9];
    const void* Ws1 = d_in[10]; const void* bs1 = d_in[11];
    const void* Wq2 = d_in[12]; const void* bq2 = d_in[13];
    const void* Wk2 = d_in[14]; const void* bk2 = d_in[15];
    const void* Wv2 = d_in[16]; const void* bv2 = d_in[17];
    const void* We2 = d_in[18];
    const void* Ws2 = d_in[19]; const void* bs2 = d_in[20];

    char* ws = (char*)d_ws;
    size_t off = 0;
    auto carve = [&](size_t bytes) -> void* {
        void* p = ws + off;
        off += (bytes + 255) & ~(size_t)255;
        return p;
    };

    u16* WtQ1 = (u16*)carve(128 * 128 * 2);
    u16* WtK1 = (u16*)carve(128 * 128 * 2);
    u16* WtV1 = (u16*)carve(128 * 128 * 2);
    u16* WtS1 = (u16*)carve(128 * 128 * 2);
    u16* WtQ2 = (u16*)carve(128 * 128 * 2);
    u16* WtK2 = (u16*)carve(128 * 128 * 2);
    u16* WtV2 = (u16*)carve(128 * 128 * 2);
    u16* WtS2 = (u16*)carve(128 * 128 * 2);
    u16* WtE1 = (u16*)carve(128 * 32 * 2);
    u16* WtE2 = (u16*)carve(128 * 32 * 2);
    int* flags   = (int*)carve(256);
    int* deg     = (int*)carve((size_t)N * 4);
    int* bsum    = (int*)carve((size_t)NB196 * 4);
    int* row_ptr = (int*)carve((size_t)(N + 1) * 4);
    int* cursor  = (int*)carve((size_t)N * 4);
    int* srcs    = (int*)carve((size_t)E * 4);
    int* eids    = (int*)carve((size_t)E * 4);
    u16* xbf = (u16*)carve((size_t)N * 128 * 2);
    u16* q  = (u16*)carve((size_t)N * 128 * 2);
    u16* k  = (u16*)carve((size_t)N * 128 * 2);
    u16* v  = (u16*)carve((size_t)N * 128 * 2);
    u16* sk = (u16*)carve((size_t)N * 128 * 2);
    u16* h  = (u16*)carve((size_t)N * 128 * 2);
    const size_t REQ_BASE = off;                        // ~81 MB
    u16* ee1 = (u16*)carve((size_t)E * 128 * 2);        // +102.4 MB
    const size_t REQ_BIG = off;                         // ~184 MB
    u16* ee2 = (u16*)carve((size_t)E * 128 * 2);        // +102.4 MB
    const size_t REQ_2EE = off;                         // ~286 MB
    const bool DUAL  = (ws_size >= REQ_2EE);
    const bool MATOK = (ws_size >= REQ_BIG);

    if (ws_size < REQ_BASE) {
        hipLaunchKernelGGL(fill_sentinel, dim3((out_size + 255) / 256), dim3(256), 0, stream,
                           (float*)d_out, out_size, 16.0f * (float)(ws_size >> 20));
        return;
    }

    hipLaunchKernelGGL(detect_fmt, dim3(1), dim3(64), 0, stream, (const u32*)x, ei, flags);

    hipLaunchKernelGGL(convert_x, dim3((N * 128 / 8 + 255) / 256), dim3(256), 0, stream,
                       x, flags, xbf, N * 128);

    TPtrs tp;
    tp.src[0] = Wq1; tp.dst[0] = WtQ1; tp.K[0] = 128;
    tp.src[1] = Wk1; tp.dst[1] = WtK1; tp.K[1] = 128;
    tp.src[2] = Wv1; tp.dst[2] = WtV1; tp.K[2] = 128;
    tp.src[3] = Ws1; tp.dst[3] = WtS1; tp.K[3] = 128;
    tp.src[4] = Wq2; tp.dst[4] = WtQ2; tp.K[4] = 128;
    tp.src[5] = Wk2; tp.dst[5] = WtK2; tp.K[5] = 128;
    tp.src[6] = Wv2; tp.dst[6] = WtV2; tp.K[6] = 128;
    tp.src[7] = Ws2; tp.dst[7] = WtS2; tp.K[7] = 128;
    tp.src[8] = We1; tp.dst[8] = WtE1; tp.K[8] = 32;
    tp.src[9] = We2; tp.dst[9] = WtE2; tp.K[9] = 32;
    hipLaunchKernelGGL(transpose_w, dim3(10, 4), dim3(256), 0, stream, tp, flags);

    (void)hipMemsetAsync(deg, 0, (size_t)N * 4, stream);
    hipLaunchKernelGGL(count_deg, dim3((E + 255) / 256), dim3(256), 0, stream, ei, flags, deg, E);
    hipLaunchKernelGGL(scan_a, dim3(NB196), dim3(256), 0, stream, deg, bsum, N);
    hipLaunchKernelGGL(scan_b, dim3(1), dim3(256), 0, stream, bsum, NB196);
    hipLaunchKernelGGL(scan_c, dim3(NB196), dim3(256), 0, stream, deg, bsum, row_ptr, cursor, N);
    hipLaunchKernelGGL(fill_csr, dim3((E + 255) / 256), dim3(256), 0, stream, ei, flags, cursor,
                       srcs, eids, E);

    const int gN = (N + 63) / 64;   // 782
    const int gE = E / 64;          // 6250
    const int gA = (N + 3) / 4;     // 12500

    if (MATOK) {
        hipLaunchKernelGGL(gemm_ee, dim3(gE), dim3(256), 0, stream,
                           eids, ef, WtE1, WtE2, flags,
                           ee1, DUAL ? ee2 : (u16*)nullptr, E);
    }

    // layer 1
    hipLaunchKernelGGL(gemm128, dim3(gN, 4), dim3(256), 0, stream,
                       xbf, flags, WtQ1, WtK1, WtV1, WtS1,
                       bq1, bk1, bv1, bs1, q, k, v, sk, N);
    if (MATOK) {
        hipLaunchKernelGGL((attn_kernel<8, 0>), dim3(gA), dim3(256), 0, stream,
                           row_ptr, srcs, q, k, v, ee1, sk, (void*)h, N);
    } else {
        hipLaunchKernelGGL((attn_fused<8, 0>), dim3(gA), dim3(256), 0, stream,
                           row_ptr, srcs, eids, flags, q, k, v, ef, We1, sk, (void*)h, N);
    }

    // layer 2
    hipLaunchKernelGGL(gemm128, dim3(gN, 4), dim3(256), 0, stream,
                       h, flags, WtQ2, WtK2, WtV2, WtS2,
                       bq2, bk2, bv2, bs2, q, k, v, sk, N);
    if (MATOK) {
        if (!DUAL) {
            hipLaunchKernelGGL(gemm_ee, dim3(gE), dim3(256), 0, stream,
                               eids, ef, WtE2, (const u16*)nullptr, flags,
                               ee1, (u16*)nullptr, E);
        }
        hipLaunchKernelGGL((attn_kernel<1, 1>), dim3(gA), dim3(256), 0, stream,
                           row_ptr, srcs, q, k, v, DUAL ? ee2 : ee1, sk, d_out, N);
    } else {
        hipLaunchKernelGGL((attn_fused<1, 1>), dim3(gA), dim3(256), 0, stream,
                           row_ptr, srcs, eids, flags, q, k, v, ef, We2, sk, d_out, N);
    }
}